// Round 1
// baseline (438.746 us; speedup 1.0000x reference)
//
#include <hip/hip_runtime.h>

// Problem constants (from setup_inputs: x (8,16,512,512) f32, inv_grid (8,512,512,2) f32)
#define BS 8
#define NC 16
#define H 512
#define W 512
#define H3 (H + 3)
#define W3 (W + 3)

// Stage 1: bilinear splat scatter-add into padded accumulator B[BS][H3][W3].
// One thread per grid point. inv_grid loaded as float2 (coalesced 8B/lane).
__global__ void splat_kernel(const float* __restrict__ inv_grid,
                             float* __restrict__ B) {
    int p = blockIdx.x * blockDim.x + threadIdx.x;
    if (p >= BS * H * W) return;
    int b = p >> (9 + 9);               // p / (H*W), H*W = 2^18

    float2 g = reinterpret_cast<const float2*>(inv_grid)[p];
    // g -> [0,1] -> padded pixel coords, clamped exactly like the reference
    // (h+1-2e-10 rounds to 513.0f in fp32)
    float gi = (g.x + 1.0f) * 0.5f * (float)H + 1.0f;
    float gj = (g.y + 1.0f) * 0.5f * (float)W + 1.0f;
    gi = fminf(fmaxf(gi, 0.0f), 513.0f);
    gj = fminf(fmaxf(gj, 0.0f), 513.0f);
    int ii = (int)gi;                    // floor (coords non-negative)
    int jj = (int)gj;

    float wi0 = fmaxf(0.0f, 1.0f - fabsf(gi - (float)ii));
    float wi1 = fmaxf(0.0f, 1.0f - fabsf(gi - (float)(ii + 1)));
    float wj0 = fmaxf(0.0f, 1.0f - fabsf(gj - (float)jj));
    float wj1 = fmaxf(0.0f, 1.0f - fabsf(gj - (float)(jj + 1)));

    float* Bb = B + (size_t)b * (H3 * W3);
    int base = ii * W3 + jj;
    atomicAdd(Bb + base,          wi0 * wj0);
    atomicAdd(Bb + base + 1,      wi0 * wj1);
    atomicAdd(Bb + base + W3,     wi1 * wj0);
    atomicAdd(Bb + base + W3 + 1, wi1 * wj1);
}

// Stage 2+3: read interior B[b, i+1, j+1], broadcast to all NC channels.
// One thread per float4 of the (b,i,j) spatial plane; 16 coalesced float4 stores.
__global__ void broadcast_kernel(const float* __restrict__ B,
                                 float* __restrict__ out) {
    int t = blockIdx.x * blockDim.x + threadIdx.x;
    if (t >= BS * H * (W / 4)) return;
    int j4   = t & (W / 4 - 1);          // t % 128
    int rest = t >> 7;                   // t / 128
    int i    = rest & (H - 1);           // rest % 512
    int b    = rest >> 9;                // rest / 512

    const float* Bp = B + ((size_t)b * H3 + (i + 1)) * W3 + (j4 * 4 + 1);
    float4 v = make_float4(Bp[0], Bp[1], Bp[2], Bp[3]);  // unaligned src: scalar reads (cache-hot)

    size_t outbase = (((size_t)b * NC) * H + i) * (size_t)W + j4 * 4;
#pragma unroll
    for (int c = 0; c < NC; ++c) {
        *reinterpret_cast<float4*>(out + outbase + (size_t)c * (H * W)) = v;
    }
}

extern "C" void kernel_launch(void* const* d_in, const int* in_sizes, int n_in,
                              void* d_out, int out_size, void* d_ws, size_t ws_size,
                              hipStream_t stream) {
    // d_in[0] = x (unused, shape-only), d_in[1] = inv_grid
    const float* inv_grid = (const float*)d_in[1];
    float* out = (float*)d_out;
    float* B = (float*)d_ws;

    const size_t Bbytes = (size_t)BS * H3 * W3 * sizeof(float);
    hipMemsetAsync(d_ws, 0, Bbytes, stream);

    const int npts = BS * H * W;                       // 2,097,152
    splat_kernel<<<(npts + 255) / 256, 256, 0, stream>>>(inv_grid, B);

    const int nq = BS * H * (W / 4);                   // 524,288
    broadcast_kernel<<<(nq + 255) / 256, 256, 0, stream>>>(B, out);
}

// Round 2
// 100.127 us; speedup vs baseline: 4.3819x; 4.3819x over previous
//
#include <hip/hip_runtime.h>

// x: (8,16,512,512) f32 (shape-only), inv_grid: (8,512,512,2) f32
#define BS 8
#define NC 16
#define H 512
#define W 512
#define W3 (W + 3)                    // 515 padded cols
#define RB 17                         // rows owned per tile
#define TPB 31                        // tiles per batch = ceil(515/17)
#define SLAB_ROWS (RB + 1)            // 18 (owned + 1 halo row)
#define PTS_PER_BATCH (H * W)         // 262144
#define NT (BS * TPB)                 // 248 tiles
#define SLAB_ELEMS (SLAB_ROWS * W3)   // 9270 floats / slab

// One workgroup per (batch, row-block) tile. Scans all of its batch's points,
// accumulates the in-range ones into an LDS slab via ds_add_f32, then plain-
// stores the slab to its private workspace slot. NO global atomics anywhere.
__global__ __launch_bounds__(1024)
void scan_splat(const float* __restrict__ inv_grid, float* __restrict__ slabs) {
    __shared__ float acc[SLAB_ELEMS];          // 37,080 B LDS
    const int tile = blockIdx.x;               // 0..247
    const int b = tile / TPB;
    const int k = tile % TPB;
    const int r0 = k * RB;

    for (int i = threadIdx.x; i < SLAB_ELEMS; i += 1024) acc[i] = 0.0f;
    __syncthreads();

    // conservative prefilter bounds on the unclamped row coord (±0.5 margin
    // covers fp reassociation; exact test below is authoritative)
    const float rlo = (k == 0)       ? -1e30f : (float)r0 - 0.5f;
    const float rhi = (k == TPB - 1) ?  1e30f : (float)(r0 + RB) + 0.5f;

    const float4* pts = reinterpret_cast<const float4*>(
        inv_grid + (size_t)b * PTS_PER_BATCH * 2);
    for (int i = threadIdx.x; i < PTS_PER_BATCH / 2; i += 1024) {
        float4 v = pts[i];                     // two points per iteration
#pragma unroll
        for (int s = 0; s < 2; ++s) {
            float gx = s ? v.z : v.x;
            float gy = s ? v.w : v.y;
            float t = fmaf(gx, 256.0f, 257.0f);     // ~gi, 1 FMA prefilter
            if (t > rlo && t < rhi) {
                // exact reference math: g->[0,1]->padded pixel coords, clamped
                // (h+1-2e-10 rounds to 513.0f in fp32)
                float gi = fminf(fmaxf((gx + 1.0f) * 0.5f * (float)H + 1.0f, 0.0f), 513.0f);
                float gj = fminf(fmaxf((gy + 1.0f) * 0.5f * (float)W + 1.0f, 0.0f), 513.0f);
                int ii = (int)gi, jj = (int)gj;
                unsigned lr = (unsigned)(ii - r0);
                if (lr < RB) {
                    float fi = gi - (float)ii, fj = gj - (float)jj;   // in [0,1)
                    float a = 1.0f - fi, c = 1.0f - fj;
                    float* p = acc + lr * W3 + jj;
                    atomicAdd(p,          a  * c);    // ds_add_f32 (LDS)
                    atomicAdd(p + 1,      a  * fj);
                    atomicAdd(p + W3,     fi * c);
                    atomicAdd(p + W3 + 1, fi * fj);
                }
            }
        }
    }
    __syncthreads();

    float* outp = slabs + (size_t)tile * SLAB_ELEMS;
    for (int i = threadIdx.x; i < SLAB_ELEMS; i += 1024) outp[i] = acc[i];
}

// Merge slab halos on the fly and broadcast the interior to all 16 channels.
// Row r (padded) lives in tile k=r/17 at local row r-17k; when local==0 the
// previous tile's halo row (local 17) also contributes.
__global__ void broadcast_merge(const float* __restrict__ slabs,
                                float* __restrict__ out) {
    int t = blockIdx.x * blockDim.x + threadIdx.x;
    if (t >= BS * H * (W / 4)) return;
    int j4   = t & 127;
    int rest = t >> 7;
    int i    = rest & 511;
    int b    = rest >> 9;

    int r  = i + 1;                      // padded row, 1..512
    int k  = r / RB;
    int lr = r - k * RB;
    const float* sp = slabs + ((size_t)(b * TPB + k) * SLAB_ROWS + lr) * W3
                    + (j4 * 4 + 1);
    float4 v;
    v.x = sp[0]; v.y = sp[1]; v.z = sp[2]; v.w = sp[3];
    if (lr == 0 && k > 0) {
        const float* hp = slabs + ((size_t)(b * TPB + k - 1) * SLAB_ROWS + RB) * W3
                        + (j4 * 4 + 1);
        v.x += hp[0]; v.y += hp[1]; v.z += hp[2]; v.w += hp[3];
    }
    size_t outbase = (((size_t)b * NC) * H + i) * (size_t)W + j4 * 4;
#pragma unroll
    for (int c = 0; c < NC; ++c)
        *reinterpret_cast<float4*>(out + outbase + (size_t)c * (H * W)) = v;
}

extern "C" void kernel_launch(void* const* d_in, const int* in_sizes, int n_in,
                              void* d_out, int out_size, void* d_ws, size_t ws_size,
                              hipStream_t stream) {
    const float* inv_grid = (const float*)d_in[1];
    float* out   = (float*)d_out;
    float* slabs = (float*)d_ws;         // 248 * 9270 * 4 B = 9.2 MB, fully overwritten

    scan_splat<<<NT, 1024, 0, stream>>>(inv_grid, slabs);

    const int nq = BS * H * (W / 4);     // 524,288 float4 positions
    broadcast_merge<<<(nq + 255) / 256, 256, 0, stream>>>(slabs, out);
}

// Round 3
// 96.608 us; speedup vs baseline: 4.5415x; 1.0364x over previous
//
#include <hip/hip_runtime.h>

// x: (8,16,512,512) f32 (shape-only), inv_grid: (8,512,512,2) f32
#define BS 8
#define NC 16
#define H 512
#define W 512
#define W3 (W + 3)                    // 515 padded cols
#define RB 17                         // rows owned per bucket
#define TPB 31                        // buckets per batch: ii in 0..513 -> ii/17 in 0..30
#define SLAB_ROWS (RB + 1)            // owned + 1 halo row
#define SLAB_ELEMS (SLAB_ROWS * W3)   // 9270 floats
#define NBUCKET (BS * TPB)            // 248
#define SCAN_BLOCKS 256               // 32 per batch
#define SBPB 32                       // scan blocks per batch
#define BPTS 8192                     // points per scan block (8192*32 = 262144 = H*W)

// K1: single-pass binning. Each block reads BPTS contiguous points of one batch,
// computes exact padded coords, buckets by k = ii/RB, ranks within (block,k)
// via the LDS-histogram atomicAdd return value, writes compacted runs.
__global__ __launch_bounds__(1024)
void bin_points(const float* __restrict__ inv_grid,
                float2* __restrict__ bins,            // [SCAN_BLOCKS*BPTS]
                unsigned* __restrict__ blockCounts) { // [SCAN_BLOCKS][32]
    __shared__ unsigned cnt[TPB];
    __shared__ unsigned off[TPB];
    const int blk = blockIdx.x;
    const int tid = threadIdx.x;
    if (tid < TPB) cnt[tid] = 0;
    __syncthreads();

    const float4* src = reinterpret_cast<const float4*>(inv_grid)
                      + (size_t)blk * (BPTS / 2);
    float2 pg[8];
    unsigned pk[8];
#pragma unroll
    for (int i = 0; i < 4; ++i) {
        float4 v = src[tid + i * 1024];               // coalesced 16B/lane
#pragma unroll
        for (int s = 0; s < 2; ++s) {
            float gx = s ? v.z : v.x;
            float gy = s ? v.w : v.y;
            // exact reference math (h+1-2e-10 rounds to 513.0f in fp32)
            float gi = fminf(fmaxf((gx + 1.0f) * 0.5f * (float)H + 1.0f, 0.0f), 513.0f);
            float gj = fminf(fmaxf((gy + 1.0f) * 0.5f * (float)W + 1.0f, 0.0f), 513.0f);
            int k = ((int)gi) / RB;                   // 0..30
            unsigned rank = atomicAdd(&cnt[k], 1u);   // in-block rank within bucket
            pg[i * 2 + s] = make_float2(gi, gj);
            pk[i * 2 + s] = ((unsigned)k << 13) | rank;   // rank < 8192
        }
    }
    __syncthreads();
    if (tid == 0) {                                   // 31-elem exclusive prefix
        unsigned run = 0;
        for (int k = 0; k < TPB; ++k) { off[k] = run; run += cnt[k]; }
    }
    if (tid < TPB) blockCounts[blk * 32 + tid] = cnt[tid];
    __syncthreads();
    float2* dst = bins + (size_t)blk * BPTS;
#pragma unroll
    for (int i = 0; i < 8; ++i) {
        unsigned k = pk[i] >> 13, r = pk[i] & 8191u;
        dst[off[k] + r] = pg[i];
    }
}

// K2: one block per bucket (b,k). Reads only its own points (all lanes active,
// no range checks), LDS-atomic splat, plain-store slab. No global atomics.
__global__ __launch_bounds__(1024)
void splat_buckets(const float2* __restrict__ bins,
                   const unsigned* __restrict__ blockCounts,
                   float* __restrict__ slabs) {
    __shared__ float acc[SLAB_ELEMS];                 // 37,080 B
    __shared__ unsigned segstart[SBPB], segn[SBPB];
    const int bucket = blockIdx.x;
    const int b = bucket / TPB, k = bucket % TPB;
    const int r0 = k * RB;
    const int tid = threadIdx.x;
    for (int i = tid; i < SLAB_ELEMS; i += 1024) acc[i] = 0.0f;
    if (tid < SBPB) {                                 // locate run in each scan block
        const unsigned* row = blockCounts + (size_t)(b * SBPB + tid) * 32;
        unsigned s = 0;
        for (int kk = 0; kk < k; ++kk) s += row[kk];
        segstart[tid] = s;
        segn[tid] = row[k];
    }
    __syncthreads();
    for (int seg = 0; seg < SBPB; ++seg) {
        const float2* base = bins + (size_t)(b * SBPB + seg) * BPTS + segstart[seg];
        unsigned n = segn[seg];
        for (unsigned idx = tid; idx < n; idx += 1024) {
            float2 p = base[idx];
            int ii = (int)p.x, jj = (int)p.y;
            float fi = p.x - (float)ii, fj = p.y - (float)jj;
            float a = 1.0f - fi, c = 1.0f - fj;
            float* q = acc + (ii - r0) * W3 + jj;
            atomicAdd(q,          a  * c);            // ds_add_f32
            atomicAdd(q + 1,      a  * fj);
            atomicAdd(q + W3,     fi * c);
            atomicAdd(q + W3 + 1, fi * fj);
        }
    }
    __syncthreads();
    float* outp = slabs + (size_t)bucket * SLAB_ELEMS;
    for (int i = tid; i < SLAB_ELEMS; i += 1024) outp[i] = acc[i];
}

// K3: merge slab halos on the fly, broadcast interior to all 16 channels.
__global__ void broadcast_merge(const float* __restrict__ slabs,
                                float* __restrict__ out) {
    int t = blockIdx.x * blockDim.x + threadIdx.x;
    if (t >= BS * H * (W / 4)) return;
    int j4   = t & 127;
    int rest = t >> 7;
    int i    = rest & 511;
    int b    = rest >> 9;

    int r  = i + 1;                      // padded row, 1..512
    int k  = r / RB;
    int lr = r - k * RB;
    const float* sp = slabs + ((size_t)(b * TPB + k) * SLAB_ROWS + lr) * W3
                    + (j4 * 4 + 1);
    float4 v;
    v.x = sp[0]; v.y = sp[1]; v.z = sp[2]; v.w = sp[3];
    if (lr == 0 && k > 0) {
        const float* hp = slabs + ((size_t)(b * TPB + k - 1) * SLAB_ROWS + RB) * W3
                        + (j4 * 4 + 1);
        v.x += hp[0]; v.y += hp[1]; v.z += hp[2]; v.w += hp[3];
    }
    size_t outbase = (((size_t)b * NC) * H + i) * (size_t)W + j4 * 4;
#pragma unroll
    for (int c = 0; c < NC; ++c)
        *reinterpret_cast<float4*>(out + outbase + (size_t)c * (H * W)) = v;
}

extern "C" void kernel_launch(void* const* d_in, const int* in_sizes, int n_in,
                              void* d_out, int out_size, void* d_ws, size_t ws_size,
                              hipStream_t stream) {
    const float* inv_grid = (const float*)d_in[1];
    float* out   = (float*)d_out;
    float* slabs = (float*)d_ws;          // 248*9270*4 = 9.2 MB, fully overwritten

    // bins (16.8 MB) + blockCounts (32 KB) live in the FRONT of d_out: they are
    // produced by K1, consumed by K2, then the whole of d_out is overwritten by
    // K3 (which reads only slabs). Keeps ws usage at the proven 9.2 MB.
    float2*   bins        = (float2*)d_out;                       // 2,097,152 float2
    unsigned* blockCounts = (unsigned*)((char*)d_out + (size_t)SCAN_BLOCKS * BPTS * 8);

    bin_points<<<SCAN_BLOCKS, 1024, 0, stream>>>(inv_grid, bins, blockCounts);
    splat_buckets<<<NBUCKET, 1024, 0, stream>>>(bins, blockCounts, slabs);

    const int nq = BS * H * (W / 4);      // 524,288 float4 positions
    broadcast_merge<<<(nq + 255) / 256, 256, 0, stream>>>(slabs, out);
}

// Round 4
// 87.783 us; speedup vs baseline: 4.9981x; 1.1005x over previous
//
#include <hip/hip_runtime.h>

// x: (8,16,512,512) f32 (shape-only), inv_grid: (8,512,512,2) f32
#define BS 8
#define NC 16
#define H 512
#define W 512
#define W3 (W + 3)                    // 515 padded cols
#define RB 17                         // rows owned per bucket
#define TPB 31                        // buckets per batch (ii in 0..513 -> ii/17 in 0..30)
#define SLAB_ROWS (RB + 1)            // owned + 1 halo row
#define SLAB_ELEMS (SLAB_ROWS * W3)   // 9270 floats
#define NBUCKET (BS * TPB)            // 248
#define SCAN_BLOCKS 512               // 64 per batch
#define SBPB 64                       // scan blocks per batch
#define BPTS 4096                     // points per scan block (4096*64 = 262144 = H*W)

// K1: binning with coalesced output. Each 512-thread block reads 4096 contiguous
// points, buckets by k = ii/RB (rank = LDS-histogram atomicAdd return), stages
// the compacted runs in LDS, then copies LDS->global fully coalesced.
__global__ __launch_bounds__(512)
void bin_points(const float* __restrict__ inv_grid,
                float2* __restrict__ bins,            // [SCAN_BLOCKS*BPTS]
                unsigned* __restrict__ blockCounts) { // [SCAN_BLOCKS][32]
    __shared__ float2 stage[BPTS];                    // 32 KB
    __shared__ unsigned cnt[TPB];
    __shared__ unsigned off[TPB];
    const int blk = blockIdx.x;
    const int tid = threadIdx.x;
    if (tid < TPB) cnt[tid] = 0;
    __syncthreads();

    const float4* src = reinterpret_cast<const float4*>(inv_grid)
                      + (size_t)blk * (BPTS / 2);
    float2 pg[8];
    unsigned pk[8];
#pragma unroll
    for (int i = 0; i < 4; ++i) {
        float4 v = src[tid + i * 512];                // coalesced 16B/lane
#pragma unroll
        for (int s = 0; s < 2; ++s) {
            float gx = s ? v.z : v.x;
            float gy = s ? v.w : v.y;
            // exact reference math (h+1-2e-10 rounds to 513.0f in fp32)
            float gi = fminf(fmaxf((gx + 1.0f) * 0.5f * (float)H + 1.0f, 0.0f), 513.0f);
            float gj = fminf(fmaxf((gy + 1.0f) * 0.5f * (float)W + 1.0f, 0.0f), 513.0f);
            int k = ((int)gi) / RB;                   // 0..30
            unsigned rank = atomicAdd(&cnt[k], 1u);   // in-block rank within bucket
            pg[i * 2 + s] = make_float2(gi, gj);
            pk[i * 2 + s] = ((unsigned)k << 12) | rank;   // rank < 4096
        }
    }
    __syncthreads();
    if (tid == 0) {                                   // 31-elem exclusive prefix
        unsigned run = 0;
        for (int k = 0; k < TPB; ++k) { off[k] = run; run += cnt[k]; }
    }
    if (tid < TPB) blockCounts[blk * 32 + tid] = cnt[tid];
    __syncthreads();
#pragma unroll
    for (int i = 0; i < 8; ++i)                       // LDS scatter (cheap)
        stage[off[pk[i] >> 12] + (pk[i] & 4095u)] = pg[i];
    __syncthreads();
    float2* dst = bins + (size_t)blk * BPTS;
    for (int i = tid; i < BPTS; i += 512) dst[i] = stage[i];  // coalesced 8B/lane
}

// K2: one block per bucket (b,k). All 64 segment runs processed CONCURRENTLY
// (16 lanes per segment), LDS-atomic splat, plain-store slab. No global atomics.
__global__ __launch_bounds__(1024)
void splat_buckets(const float2* __restrict__ bins,
                   const unsigned* __restrict__ blockCounts,
                   float* __restrict__ slabs) {
    __shared__ float acc[SLAB_ELEMS];                 // 37,080 B
    __shared__ unsigned segstart[SBPB], segn[SBPB];
    const int bucket = blockIdx.x;
    const int b = bucket / TPB, k = bucket % TPB;
    const int r0 = k * RB;
    const int tid = threadIdx.x;
    for (int i = tid; i < SLAB_ELEMS; i += 1024) acc[i] = 0.0f;
    if (tid < SBPB) {                                 // locate this bucket's run
        const unsigned* row = blockCounts + (size_t)(b * SBPB + tid) * 32;
        unsigned s = 0;
        for (int kk = 0; kk < k; ++kk) s += row[kk];
        segstart[tid] = s;
        segn[tid] = row[k];
    }
    __syncthreads();

    const int seg  = tid >> 4;                        // 64 segments in flight
    const int lane = tid & 15;
    const float2* base = bins + (size_t)(b * SBPB + seg) * BPTS + segstart[seg];
    const unsigned n = segn[seg];
    for (unsigned idx = lane; idx < n; idx += 16) {   // ~9 iters, all waves active
        float2 p = base[idx];
        int ii = (int)p.x, jj = (int)p.y;
        float fi = p.x - (float)ii, fj = p.y - (float)jj;
        float a = 1.0f - fi, c = 1.0f - fj;
        float* q = acc + (ii - r0) * W3 + jj;
        atomicAdd(q,          a  * c);                // ds_add_f32
        atomicAdd(q + 1,      a  * fj);
        atomicAdd(q + W3,     fi * c);
        atomicAdd(q + W3 + 1, fi * fj);
    }
    __syncthreads();
    float* outp = slabs + (size_t)bucket * SLAB_ELEMS;
    for (int i = tid; i < SLAB_ELEMS; i += 1024) outp[i] = acc[i];
}

// K3: merge slab halos on the fly, broadcast interior to all 16 channels.
__global__ void broadcast_merge(const float* __restrict__ slabs,
                                float* __restrict__ out) {
    int t = blockIdx.x * blockDim.x + threadIdx.x;
    if (t >= BS * H * (W / 4)) return;
    int j4   = t & 127;
    int rest = t >> 7;
    int i    = rest & 511;
    int b    = rest >> 9;

    int r  = i + 1;                      // padded row, 1..512
    int k  = r / RB;
    int lr = r - k * RB;
    const float* sp = slabs + ((size_t)(b * TPB + k) * SLAB_ROWS + lr) * W3
                    + (j4 * 4 + 1);
    float4 v;
    v.x = sp[0]; v.y = sp[1]; v.z = sp[2]; v.w = sp[3];
    if (lr == 0 && k > 0) {
        const float* hp = slabs + ((size_t)(b * TPB + k - 1) * SLAB_ROWS + RB) * W3
                        + (j4 * 4 + 1);
        v.x += hp[0]; v.y += hp[1]; v.z += hp[2]; v.w += hp[3];
    }
    size_t outbase = (((size_t)b * NC) * H + i) * (size_t)W + j4 * 4;
#pragma unroll
    for (int c = 0; c < NC; ++c)
        *reinterpret_cast<float4*>(out + outbase + (size_t)c * (H * W)) = v;
}

extern "C" void kernel_launch(void* const* d_in, const int* in_sizes, int n_in,
                              void* d_out, int out_size, void* d_ws, size_t ws_size,
                              hipStream_t stream) {
    const float* inv_grid = (const float*)d_in[1];
    float* out   = (float*)d_out;
    float* slabs = (float*)d_ws;          // 248*9270*4 = 9.2 MB

    // bins (16.8 MB) + blockCounts (64 KB) live in the FRONT of d_out: produced
    // by K1, consumed by K2, then d_out is fully overwritten by K3 (reads only
    // slabs). Every byte K2 reads is written by K1 on every call (deterministic).
    float2*   bins        = (float2*)d_out;                       // 2,097,152 float2
    unsigned* blockCounts = (unsigned*)((char*)d_out + (size_t)SCAN_BLOCKS * BPTS * 8);

    bin_points<<<SCAN_BLOCKS, 512, 0, stream>>>(inv_grid, bins, blockCounts);
    splat_buckets<<<NBUCKET, 1024, 0, stream>>>(bins, blockCounts, slabs);

    const int nq = BS * H * (W / 4);      // 524,288 float4 positions
    broadcast_merge<<<(nq + 255) / 256, 256, 0, stream>>>(slabs, out);
}